// Round 3
// baseline (218.587 us; speedup 1.0000x reference)
//
#include <hip/hip_runtime.h>

#define B_SZ 1024
#define DIN 512
#define HH 512   // H
#define DOUT 512

typedef short bf16x8 __attribute__((ext_vector_type(8)));
typedef float f32x4 __attribute__((ext_vector_type(4)));

__device__ __forceinline__ unsigned short f2bf(float f) {
    unsigned int u = __float_as_uint(f);
    u += 0x7FFFu + ((u >> 16) & 1u);          // RTNE
    return (unsigned short)(u >> 16);
}
__device__ __forceinline__ float bf2f(unsigned short s) {
    return __uint_as_float(((unsigned int)s) << 16);
}

// ---------------------------------------------------------------------------
// bf16 hi/lo split GEMM scheme (K'=1536 = 3 terms x 512):
//   C = AhiWhi + AloWhi + AhiWlo  (~fp32 accurate)
// A-side terms over k' in [0,512)=hi, [512,1024)=lo, [1024,1536)=hi.
// B-side terms: hi, hi, lo.  A is converted ON THE FLY in gemm staging
// (saves the conv_h dispatch + global round-trip); B is prepped once.
// B layout Bfr[48 ks][32 nf][64 lanes]{uint4}: elem (lane,j) =
//   Wsplit[ks*32 + (lane>>4)*8 + j][nf*16 + (lane&15)].
// Only lane&15 = row/col + the m89-verified C/D layout matter; the k'<->j
// map is the same bijection on both operands.
// ---------------------------------------------------------------------------
__device__ __forceinline__ void convW_body(const float* __restrict__ W,
                                           uint4* __restrict__ dst, int t) {
    const int lane = t & 63;
    const int fb   = t >> 6;         // ks*32 + nf
    const int ks   = fb >> 5;
    const int nf   = fb & 31;
    const int col  = nf * 16 + (lane & 15);
    const int kb   = ks * 32 + ((lane >> 4) << 3);
    const int term = kb >> 9;        // 0,1,2 -> hi,hi,lo
    const int c0   = kb & 511;
    unsigned short o[8];
    #pragma unroll
    for (int j = 0; j < 8; ++j) {
        const float f = W[(size_t)(c0 + j) * 512 + col];
        unsigned short hi = f2bf(f);
        o[j] = (term == 2) ? f2bf(f - bf2f(hi)) : hi;
    }
    uint4 v;
    v.x = (unsigned int)o[0] | ((unsigned int)o[1] << 16);
    v.y = (unsigned int)o[2] | ((unsigned int)o[3] << 16);
    v.z = (unsigned int)o[4] | ((unsigned int)o[5] << 16);
    v.w = (unsigned int)o[6] | ((unsigned int)o[7] << 16);
    dst[t] = v;
}

// ---------------------------------------------------------------------------
// prep_all: fused (block-range dispatch)
//   [0,1022)     wb[i][j] = (j>i) ? {W_hh,b_hh} : {0,-1}   (scan weights)
//   [1022,1406)  W_in  -> Bin  (384 blocks)
//   [1406,1790)  W_out -> Bout (384 blocks)
// ---------------------------------------------------------------------------
__global__ __launch_bounds__(256)
void prep_all(const float* __restrict__ W_hh, const float* __restrict__ b_hh,
              float2* __restrict__ wb,
              const float* __restrict__ W_in, uint4* __restrict__ Bin,
              const float* __restrict__ W_out, uint4* __restrict__ Bout) {
    const int b = blockIdx.x;
    const int tid = threadIdx.x;
    if (b < 1022) {
        const int idx = b * 256 + tid;       // over (H-1)*H
        const int i = idx >> 9;
        const int j = idx & 511;
        float2 o;
        if (j > i) { o.x = W_hh[idx]; o.y = b_hh[idx]; }
        else       { o.x = 0.0f;      o.y = -1.0f;     }
        wb[idx] = o;
    } else if (b < 1406) {
        convW_body(W_in, Bin, (b - 1022) * 256 + tid);
    } else {
        convW_body(W_out, Bout, (b - 1406) * 256 + tid);
    }
}

// ---------------------------------------------------------------------------
// MFMA GEMM with fused A-side fp32 -> bf16 hi/lo split in staging.
// C[1024,512] = act(A @ W + bias); A fp32 [1024][512]; B pre-split (Bfr).
// Tile 64x32, grid 16x16 = 256 blocks (1/CU), 4 waves. Relay regs hold RAW
// fp32 A-data; conversion happens at LDS-write time (after the natural
// waitcnt), keeping load-issue -> use distance = 1 full tile as before.
// ---------------------------------------------------------------------------
template <bool ACT>
__global__ __launch_bounds__(256, 1)
void mfma_gemm(const float* __restrict__ A,    // [1024][512] fp32
               const uint4* __restrict__ Bg,   // [48][32][64] uint4
               const float* __restrict__ bias,
               float* __restrict__ C) {
    __shared__ uint4 lds[2][768];              // per buf: A 512, B 256
    const int tid  = threadIdx.x;
    const int lane = tid & 63;
    const int w    = tid >> 6;
    const int wr   = w & 1;
    const int wc   = w >> 1;
    const int mf0  = blockIdx.x * 4;
    const int nf0  = blockIdx.y * 2;

    const int a_mfs = (tid >> 6) & 3;          // staging: A mf slot
    const int b_ks  = tid >> 7;                // staging: B ks slot
    const int b_nfs = (tid >> 6) & 1;          // staging: B nf slot

    const int arow = (mf0 + a_mfs) * 16 + (lane & 15);
    const int koff = (lane >> 4) << 3;         // 0,8,16,24

    float4 Ra0, Ra1, Rb0, Rb1;                 // raw fp32 relay (2 ks slots)
    uint4  R2;                                 // B relay (pre-split)
    auto stage = [&](int s) {
        const int ks0 = s * 2;
        const int c0 = (ks0 * 32 + koff) & 511;
        const int c1 = ((ks0 + 1) * 32 + koff) & 511;
        Ra0 = *(const float4*)&A[(size_t)arow * 512 + c0];
        Ra1 = *(const float4*)&A[(size_t)arow * 512 + c0 + 4];
        Rb0 = *(const float4*)&A[(size_t)arow * 512 + c1];
        Rb1 = *(const float4*)&A[(size_t)arow * 512 + c1 + 4];
        R2  = Bg[(size_t)((ks0 + b_ks) * 32 + nf0 + b_nfs) * 64 + lane];
    };

    auto cvt8 = [&](const float4& a0, const float4& a1, int term) -> uint4 {
        const float av[8] = {a0.x, a0.y, a0.z, a0.w, a1.x, a1.y, a1.z, a1.w};
        unsigned int p[4];
        #pragma unroll
        for (int q = 0; q < 4; ++q) {
            float f0 = av[2 * q], f1 = av[2 * q + 1];
            unsigned short h0 = f2bf(f0), h1 = f2bf(f1);
            if (term == 1) {                   // wave-uniform branch
                h0 = f2bf(f0 - bf2f(h0));
                h1 = f2bf(f1 - bf2f(h1));
            }
            p[q] = (unsigned int)h0 | ((unsigned int)h1 << 16);
        }
        uint4 v; v.x = p[0]; v.y = p[1]; v.z = p[2]; v.w = p[3];
        return v;
    };
    // write relay (holding tile s) into LDS buffer `buf`
    auto write_tile = [&](int buf, int s) {
        const int ks0 = s * 2;
        lds[buf][tid]       = cvt8(Ra0, Ra1, ks0 >> 4);
        lds[buf][256 + tid] = cvt8(Rb0, Rb1, (ks0 + 1) >> 4);
        lds[buf][512 + tid] = R2;
    };

    f32x4 acc0 = {0.f, 0.f, 0.f, 0.f};
    f32x4 acc1 = {0.f, 0.f, 0.f, 0.f};

    stage(0);
    write_tile(0, 0);
    stage(1);
    __syncthreads();

    for (int s = 0; s < 24; ++s) {
        const int cur = s & 1;
        if (s + 1 < 24) write_tile(cur ^ 1, s + 1);   // convert+write relay
        if (s + 2 < 24) stage(s + 2);                 // prefetch tile s+2
        __builtin_amdgcn_sched_barrier(0);            // pin loads above MFMAs

        bf16x8 aF[2][2], bF[2];
        #pragma unroll
        for (int ksL = 0; ksL < 2; ++ksL) {
            #pragma unroll
            for (int mfL = 0; mfL < 2; ++mfL)
                aF[ksL][mfL] = *(const bf16x8*)&lds[cur][ksL * 256 + (wr * 2 + mfL) * 64 + lane];
            bF[ksL] = *(const bf16x8*)&lds[cur][512 + (ksL * 2 + wc) * 64 + lane];
        }
        #pragma unroll
        for (int ksL = 0; ksL < 2; ++ksL) {
            acc0 = __builtin_amdgcn_mfma_f32_16x16x32_bf16(aF[ksL][0], bF[ksL], acc0, 0, 0, 0);
            acc1 = __builtin_amdgcn_mfma_f32_16x16x32_bf16(aF[ksL][1], bF[ksL], acc1, 0, 0, 0);
        }
        __syncthreads();
    }

    // epilogue: C/D layout (m89-verified): col = lane&15, row = (lane>>4)*4 + r
    const int colg   = (nf0 + wc) * 16 + (lane & 15);
    const float bv   = bias[colg];
    const int rbase0 = (mf0 + wr * 2) * 16 + ((lane >> 4) << 2);
    #pragma unroll
    for (int r = 0; r < 4; ++r) {
        float v = acc0[r] + bv;
        if (ACT) { v = fmaxf(v, 0.f); v = v * v; }
        C[(size_t)(rbase0 + r) * 512 + colg] = v;
    }
    #pragma unroll
    for (int r = 0; r < 4; ++r) {
        float v = acc1[r] + bv;
        if (ACT) { v = fmaxf(v, 0.f); v = v * v; }
        C[(size_t)(rbase0 + 16 + r) * 512 + colg] = v;
    }
}

// ---------------------------------------------------------------------------
// Sequential triangular scan, v4: blocked diag + streaming bulk.
// 256 blocks x 4 waves; wave = one batch row; lane l owns cols l+64k.
// Per 64-step chunk C:
//   1) preload the 64-step diagonal weights (1 float2/lane/step -> 128 VGPRs)
//      and the first D bulk i-steps into a static register window;
//   2) run the 64-step serial chain ENTIRELY from registers (readlane ->
//      fmaf -> fmax -> fmaf, ~25 cyc/step, no memory on the chain);
//   3) stream the bulk (groups k>C, 7/8 of all work): hr[C] is final, so
//      all 64 readlanes are independent -> D-deep pipelined weight stream.
// __launch_bounds__(256,1) is ESSENTIAL: with plain (256) the compiler caps
// at 64 VGPRs (8-wave occupancy target) and sinks the window loads, putting
// an exposed L2 latency on every serial step (v3: 324 cyc/step measured).
// FP accumulation order per column is unchanged vs v2/v3.
// ---------------------------------------------------------------------------
template <int C>
__device__ __forceinline__ void scan_chunk(const float2* __restrict__ wb,
                                           float hr[8], int lane) {
    constexpr int NK = 7 - C;                               // bulk groups
    constexpr int D  = (NK >= 4) ? 8 : (NK >= 2) ? 16 : 32; // window depth
    const float2* rowp = wb + (size_t)(64 * C) * HH + lane; // chunk row base

    __syncthreads();   // keep 4 waves lockstep -> L1 serves the shared stream

    // 1a) diagonal block preload: Wd[s] = wb[(64C+s)*512 + 64C + lane]
    //     (C=7,s=63 reads in-workspace pad; its compute is skipped below)
    float2 Wd[64];
    #pragma unroll
    for (int s = 0; s < 64; ++s)
        Wd[s] = rowp[(size_t)s * HH + 64 * C];

    // 1b) bulk window preload: first D i-steps x NK groups
    float2 Wb[NK > 0 ? D : 1][NK > 0 ? NK : 1];
    if constexpr (NK > 0) {
        #pragma unroll
        for (int q = 0; q < D; ++q)
            #pragma unroll
            for (int k = 0; k < NK; ++k)
                Wb[q][k] = rowp[(size_t)q * HH + 64 * (C + 1 + k)];
    }
    asm volatile("s_waitcnt vmcnt(0)");
    __builtin_amdgcn_sched_barrier(0);         // loads stay issued above here

    // 2) serial diagonal: 64 steps, registers only
    #pragma unroll
    for (int s = 0; s < 64; ++s) {
        if (!(C == 7 && s == 63)) {            // no global step 511
            const float hi = __uint_as_float(
                __builtin_amdgcn_readlane(__float_as_uint(hr[C]), s));
            const float tv = fmaf(hi, Wd[s].x, Wd[s].y);
            const float rv = fmaxf(tv, 0.f);
            hr[C] = fmaf(rv, rv, hr[C]);
        }
    }

    // 3) streaming bulk: i = 0..63 over groups C+1..7, D-deep pipeline
    if constexpr (NK > 0) {
        constexpr int NT = 64 / D;
        for (int t = 0; t < NT; ++t) {
            #pragma unroll
            for (int q = 0; q < D; ++q) {
                const int i = t * D + q;       // runtime-uniform
                const float hi = __uint_as_float(
                    __builtin_amdgcn_readlane(__float_as_uint(hr[C]), i));
                #pragma unroll
                for (int k = 0; k < NK; ++k) {
                    const float tv = fmaf(hi, Wb[q][k].x, Wb[q][k].y);
                    const float rv = fmaxf(tv, 0.f);
                    hr[C + 1 + k] = fmaf(rv, rv, hr[C + 1 + k]);
                }
                if (t + 1 < NT) {              // refill slot q with step i+D
                    #pragma unroll
                    for (int k = 0; k < NK; ++k)
                        Wb[q][k] = rowp[(size_t)(i + D) * HH + 64 * (C + 1 + k)];
                }
            }
            __builtin_amdgcn_sched_barrier(0); // refills stay above next group
        }
    }
}

__global__ __launch_bounds__(256, 1)
void scan_kernel(const float2* __restrict__ wb, float* __restrict__ h) {
    const int lane = threadIdx.x & 63;
    const int wave = threadIdx.x >> 6;
    const int row  = blockIdx.x * 4 + wave;    // 256 blocks x 4 indep waves
    float* hrow = h + (size_t)row * HH;

    float hr[8];
    #pragma unroll
    for (int k = 0; k < 8; ++k) hr[k] = hrow[lane + 64 * k];

    scan_chunk<0>(wb, hr, lane);
    scan_chunk<1>(wb, hr, lane);
    scan_chunk<2>(wb, hr, lane);
    scan_chunk<3>(wb, hr, lane);
    scan_chunk<4>(wb, hr, lane);
    scan_chunk<5>(wb, hr, lane);
    scan_chunk<6>(wb, hr, lane);
    scan_chunk<7>(wb, hr, lane);

    #pragma unroll
    for (int k = 0; k < 8; ++k) hrow[lane + 64 * k] = hr[k];
}

// ---------------------------------------------------------------------------
// workspace layout (7 MB):
//   [0x000000, 0x200000) wb   (511*512 float2; row-511 pad read stays inside)
//   [0x200000, 0x400000) h    (1024*512 fp32)
//   [0x400000, 0x580000) Bin  (48*32*64 uint4 = 1.5 MB)
//   [0x580000, 0x700000) Bout (1.5 MB)
// ---------------------------------------------------------------------------
extern "C" void kernel_launch(void* const* d_in, const int* in_sizes, int n_in,
                              void* d_out, int out_size, void* d_ws, size_t ws_size,
                              hipStream_t stream) {
    const float* x     = (const float*)d_in[0];
    const float* W_in  = (const float*)d_in[1];
    const float* b_in  = (const float*)d_in[2];
    const float* W_hh  = (const float*)d_in[3];
    const float* b_hh  = (const float*)d_in[4];
    const float* W_out = (const float*)d_in[5];
    const float* b_out = (const float*)d_in[6];
    float* out = (float*)d_out;

    char* ws = (char*)d_ws;
    float2* wb   = (float2*)ws;
    float*  h    = (float*)(ws + 0x200000u);
    uint4*  Bin  = (uint4*)(ws + 0x400000u);
    uint4*  Bout = (uint4*)(ws + 0x580000u);

    // 1) prep: wb mask-interleave + W_in/W_out bf16 hi/lo frag-linear split
    prep_all<<<dim3(1790), dim3(256), 0, stream>>>(W_hh, b_hh, wb,
                                                   W_in, Bin, W_out, Bout);

    // 2) h0 = relu^2(x @ W_in + b_in)  (A-side split fused into staging)
    mfma_gemm<true><<<dim3(16, 16), dim3(256), 0, stream>>>(x, Bin, b_in, h);

    // 3) sequential triangular scan, in-place on h (diag+bulk register pipeline)
    scan_kernel<<<dim3(256), dim3(256), 0, stream>>>(wb, h);

    // 4) out = h @ W_out + b_out  (A-side split fused into staging)
    mfma_gemm<false><<<dim3(16, 16), dim3(256), 0, stream>>>(h, Bout, b_out, out);
}

// Round 5
// 175.463 us; speedup vs baseline: 1.2458x; 1.2458x over previous
//
#include <hip/hip_runtime.h>

#define B_SZ 1024
#define DIN 512
#define HH 512   // H
#define DOUT 512

typedef short bf16x8 __attribute__((ext_vector_type(8)));
typedef float f32x4 __attribute__((ext_vector_type(4)));

__device__ __forceinline__ unsigned short f2bf(float f) {
    unsigned int u = __float_as_uint(f);
    u += 0x7FFFu + ((u >> 16) & 1u);          // RTNE
    return (unsigned short)(u >> 16);
}
__device__ __forceinline__ float bf2f(unsigned short s) {
    return __uint_as_float(((unsigned int)s) << 16);
}

// pack 8 fp32 -> 8 bf16 (term==1 -> lo residual, else hi)
__device__ __forceinline__ uint4 cvt8(const float4& a0, const float4& a1, int term) {
    const float av[8] = {a0.x, a0.y, a0.z, a0.w, a1.x, a1.y, a1.z, a1.w};
    unsigned int p[4];
    #pragma unroll
    for (int q = 0; q < 4; ++q) {
        float f0 = av[2 * q], f1 = av[2 * q + 1];
        unsigned short h0 = f2bf(f0), h1 = f2bf(f1);
        if (term == 1) { h0 = f2bf(f0 - bf2f(h0)); h1 = f2bf(f1 - bf2f(h1)); }
        p[q] = (unsigned int)h0 | ((unsigned int)h1 << 16);
    }
    uint4 v; v.x = p[0]; v.y = p[1]; v.z = p[2]; v.w = p[3];
    return v;
}

// ---------------------------------------------------------------------------
// bf16 hi/lo split GEMM scheme (K'=1536 = 3 terms x 512):
//   C = AhiWhi + AloWhi + AhiWlo  (~fp32 accurate)
// A terms over k': hi, lo, hi (converted on the fly in gemm staging).
// B terms: hi, hi, lo (prepped once into Bfr[48 ks][32 nf][64 lanes]{uint4},
//   elem (lane,j) = Wsplit[ks*32 + (lane>>4)*8 + j][nf*16 + (lane&15)]).
// ---------------------------------------------------------------------------
__device__ __forceinline__ void convW_body(const float* __restrict__ W,
                                           uint4* __restrict__ dst, int t) {
    const int lane = t & 63;
    const int fb   = t >> 6;         // ks*32 + nf
    const int ks   = fb >> 5;
    const int nf   = fb & 31;
    const int col  = nf * 16 + (lane & 15);
    const int kb   = ks * 32 + ((lane >> 4) << 3);
    const int term = kb >> 9;        // 0,1,2 -> hi,hi,lo
    const int c0   = kb & 511;
    unsigned short o[8];
    #pragma unroll
    for (int j = 0; j < 8; ++j) {
        const float f = W[(size_t)(c0 + j) * 512 + col];
        unsigned short hi = f2bf(f);
        o[j] = (term == 2) ? f2bf(f - bf2f(hi)) : hi;
    }
    uint4 v;
    v.x = (unsigned int)o[0] | ((unsigned int)o[1] << 16);
    v.y = (unsigned int)o[2] | ((unsigned int)o[3] << 16);
    v.z = (unsigned int)o[4] | ((unsigned int)o[5] << 16);
    v.w = (unsigned int)o[6] | ((unsigned int)o[7] << 16);
    dst[t] = v;
}

// scan weight packing, consumption-ordered:
//  wdg[i*64 + l] = diag-block elem (row i, col 64*(i>>6)+l), masked (j>i), row 511 pad
//  wbk[CB(C) + (s*NK + k)*64 + l] = bulk elem (row 64C+s, col 64*(C+1+k)+l), no mask needed
template <int C>
__device__ __forceinline__ void pack_bulk(const float* __restrict__ W_hh,
                                          const float* __restrict__ b_hh,
                                          float2* __restrict__ wbk, int e) {
    constexpr int NK = 7 - C;
    constexpr int CB = (C==0?0:C==1?7:C==2?13:C==3?18:C==4?22:C==5?25:27) * 4096;
    const int s   = e / (NK * 64);           // compile-time NK -> magic mul
    const int rem = e - s * (NK * 64);
    const int row = 64 * C + s;
    const int col = 64 * (C + 1) + rem;      // = 64*(C+1+k)+l
    float2 o;
    o.x = W_hh[(size_t)row * 512 + col];
    o.y = b_hh[(size_t)row * 512 + col];
    wbk[CB + e] = o;
}

// ---------------------------------------------------------------------------
// prep_all (block-range dispatch), 1344 blocks:
//   [0,128)      wdg diag pack (512 x 64 f2)
//   [128,576)    wbk bulk pack (114688 f2); chunk block starts 0,112,208,288,352,400,432
//   [576,960)    W_in  -> Bin
//   [960,1344)   W_out -> Bout
// ---------------------------------------------------------------------------
__global__ __launch_bounds__(256)
void prep_all(const float* __restrict__ W_hh, const float* __restrict__ b_hh,
              float2* __restrict__ wdg, float2* __restrict__ wbk,
              const float* __restrict__ W_in, uint4* __restrict__ Bin,
              const float* __restrict__ W_out, uint4* __restrict__ Bout) {
    const int b = blockIdx.x;
    const int tid = threadIdx.x;
    if (b < 128) {
        const int idx = b * 256 + tid;       // over 512*64
        const int i = idx >> 6, l = idx & 63;
        float2 o;
        if (i < 511 && l > (i & 63)) {
            const int col = ((i >> 6) << 6) + l;
            o.x = W_hh[(size_t)i * 512 + col];
            o.y = b_hh[(size_t)i * 512 + col];
        } else { o.x = 0.0f; o.y = -1.0f; }
        wdg[idx] = o;
    } else if (b < 576) {
        const int rb = b - 128;
        if      (rb < 112) pack_bulk<0>(W_hh, b_hh, wbk, (rb      ) * 256 + tid);
        else if (rb < 208) pack_bulk<1>(W_hh, b_hh, wbk, (rb - 112) * 256 + tid);
        else if (rb < 288) pack_bulk<2>(W_hh, b_hh, wbk, (rb - 208) * 256 + tid);
        else if (rb < 352) pack_bulk<3>(W_hh, b_hh, wbk, (rb - 288) * 256 + tid);
        else if (rb < 400) pack_bulk<4>(W_hh, b_hh, wbk, (rb - 352) * 256 + tid);
        else if (rb < 432) pack_bulk<5>(W_hh, b_hh, wbk, (rb - 400) * 256 + tid);
        else               pack_bulk<6>(W_hh, b_hh, wbk, (rb - 432) * 256 + tid);
    } else if (b < 960) {
        convW_body(W_in, Bin, (b - 576) * 256 + tid);
    } else {
        convW_body(W_out, Bout, (b - 960) * 256 + tid);
    }
}

// ---------------------------------------------------------------------------
// MFMA GEMM v2: 512 threads (8 waves = 2/SIMD for latency hiding).
// C[1024,512] = act(A @ W + bias); A fp32 (split fused in staging); B prepped.
// Tile 64x32, grid (16,16) = 256 blocks = 1/CU. Wave w -> (mf=w&3, nf=w>>2),
// 2 MFMA/iter into one f32x4 acc. Single barrier/iter + 2-tile relay lookahead.
// ---------------------------------------------------------------------------
template <bool ACT>
__global__ __launch_bounds__(512, 2)
void mfma_gemm(const float* __restrict__ A,    // [1024][512] fp32
               const uint4* __restrict__ Bg,   // [48][32][64] uint4
               const float* __restrict__ bias,
               float* __restrict__ C) {
    __shared__ uint4 lds[2][768];   // per buf: A[ks*256+mf*64+lane], B at 512+[ks*128+nf*64+lane]
    const int tid  = threadIdx.x;
    const int lane = tid & 63;
    const int w    = tid >> 6;       // 0..7
    const int mfw  = w & 3;          // compute: A frag
    const int nfw  = w >> 2;         // compute: B frag 0..1
    const int mf0  = blockIdx.x * 4;
    const int nf0  = blockIdx.y * 2;

    const int ks_s = tid >> 8;               // A staging: ks slot 0..1
    const int mf_s = (tid >> 6) & 3;         // A staging: mf slot
    const int arow = (mf0 + mf_s) * 16 + (lane & 15);
    const int koff = (lane >> 4) << 3;       // 0,8,16,24
    const int bks  = tid >> 7;               // B staging (tid<256): ks slot
    const int bnf  = (tid >> 6) & 1;         // B staging: nf slot

    float4 Ra0, Ra1; uint4 R2;
    auto stage = [&](int s) {
        const int kp = (s * 2 + ks_s) * 32 + koff;
        const int c  = kp & 511;
        Ra0 = *(const float4*)&A[(size_t)arow * 512 + c];
        Ra1 = *(const float4*)&A[(size_t)arow * 512 + c + 4];
        if (tid < 256)
            R2 = Bg[(size_t)((s * 2 + bks) * 32 + nf0 + bnf) * 64 + lane];
    };
    auto write_tile = [&](int buf, int s) {
        const int kp = (s * 2 + ks_s) * 32 + koff;
        lds[buf][ks_s * 256 + mf_s * 64 + lane] = cvt8(Ra0, Ra1, kp >> 9);
        if (tid < 256)
            lds[buf][512 + bks * 128 + bnf * 64 + lane] = R2;
    };

    f32x4 acc = {0.f, 0.f, 0.f, 0.f};

    stage(0);
    write_tile(0, 0);
    stage(1);
    __syncthreads();

    for (int s = 0; s < 24; ++s) {
        const int cur = s & 1;
        if (s + 1 < 24) write_tile(cur ^ 1, s + 1);   // convert+write relay
        if (s + 2 < 24) stage(s + 2);                 // prefetch tile s+2
        __builtin_amdgcn_sched_barrier(0);            // pin loads above MFMAs

        bf16x8 aF0 = *(const bf16x8*)&lds[cur][        mfw * 64 + lane];
        bf16x8 aF1 = *(const bf16x8*)&lds[cur][256   + mfw * 64 + lane];
        bf16x8 bF0 = *(const bf16x8*)&lds[cur][512   + nfw * 64 + lane];
        bf16x8 bF1 = *(const bf16x8*)&lds[cur][512+128 + nfw * 64 + lane];
        acc = __builtin_amdgcn_mfma_f32_16x16x32_bf16(aF0, bF0, acc, 0, 0, 0);
        acc = __builtin_amdgcn_mfma_f32_16x16x32_bf16(aF1, bF1, acc, 0, 0, 0);
        __syncthreads();
    }

    // epilogue: C/D layout (m89-verified): col = lane&15, row = (lane>>4)*4 + r
    const int colg  = (nf0 + nfw) * 16 + (lane & 15);
    const float bv  = bias[colg];
    const int rbase = (mf0 + mfw) * 16 + ((lane >> 4) << 2);
    #pragma unroll
    for (int r = 0; r < 4; ++r) {
        float v = acc[r] + bv;
        if (ACT) { v = fmaxf(v, 0.f); v = v * v; }
        C[(size_t)(rbase + r) * 512 + colg] = v;
    }
}

// ---------------------------------------------------------------------------
// Sequential triangular scan, v5b: diag + bulk from CONSUMPTION-ORDERED packs.
// 256 blocks x 4 waves; wave = one batch row; lane l owns cols l+64k.
// Per 64-step chunk C:
//   - rotating DD=16 diag window from wdg (32 regs; 16-step chain round-trip
//     ~320 cyc covers L2 latency; small sequential offsets -> cheap addressing)
//   - D x NK bulk window from wbk, preloaded before the diag chain (latency
//     hides under it), refilled slot-by-slot during the streaming bulk pass.
// Peak ~120 VGPR -> no spill (v4 failed here: 64 unrolled 4KB-strided preloads
// needed 128 data + 128 address regs -> alloc stopped at 172 and spilled).
// v5b: raw s_barrier (NO vmcnt drain, unlike __syncthreads -> relay prefetch
// stays in flight) between tiles keeps the 4 waves/CU within one <=28KB tile
// of the shared weight stream so L1 serves 3 of 4 waves' reads. No memory is
// communicated across the barrier -> skipping the waitcnt is safe.
// FP accumulation order per column unchanged -> same numerics as v2-v4.
// ---------------------------------------------------------------------------
template <int C>
__device__ __forceinline__ void scan_chunk(const float2* __restrict__ wdg,
                                           const float2* __restrict__ wbk,
                                           float hr[8], int lane) {
    constexpr int NK = 7 - C;
    constexpr int DD = 16;                                   // diag window
    constexpr int D  = (NK >= 6) ? 4 : (NK >= 3) ? 8 : 16;   // bulk window depth
    constexpr int CB = (C==0?0:C==1?7:C==2?13:C==3?18:C==4?22:C==5?25:C==6?27:28) * 4096;

    const float2* dptr = wdg + (64 * C) * 64 + lane;
    const float2* bptr = wbk + CB + lane;

    __syncthreads();   // chunk top: full resync of the 4 waves

    float2 Wd[DD];
    #pragma unroll
    for (int q = 0; q < DD; ++q) Wd[q] = dptr[q * 64];

    float2 Wb[NK > 0 ? D : 1][NK > 0 ? NK : 1];
    if constexpr (NK > 0) {
        #pragma unroll
        for (int q = 0; q < D; ++q)
            #pragma unroll
            for (int k = 0; k < NK; ++k)
                Wb[q][k] = bptr[(q * NK + k) * 64];
    }
    __builtin_amdgcn_sched_barrier(0);         // preloads stay issued above

    // serial diagonal: 64 steps, rotating register window
    for (int t = 0; t < 64 / DD; ++t) {
        #pragma unroll
        for (int q = 0; q < DD; ++q) {
            const int s = t * DD + q;
            if (!(C == 7 && s == 63)) {        // no global step 511
                const float hi = __uint_as_float(
                    __builtin_amdgcn_readlane(__float_as_uint(hr[C]), s));
                const float tv = fmaf(hi, Wd[q].x, Wd[q].y);
                const float rv = fmaxf(tv, 0.f);
                hr[C] = fmaf(rv, rv, hr[C]);
            }
            if (t + 1 < 64 / DD) Wd[q] = dptr[(s + DD) * 64];
        }
        __builtin_amdgcn_s_barrier();          // lockstep, no vmcnt drain
    }

    // streaming bulk: hr[C] final -> all readlanes independent
    if constexpr (NK > 0) {
        constexpr int NT = 64 / D;
        for (int t = 0; t < NT; ++t) {
            #pragma unroll
            for (int q = 0; q < D; ++q) {
                const int i = t * D + q;
                const float hi = __uint_as_float(
                    __builtin_amdgcn_readlane(__float_as_uint(hr[C]), i));
                #pragma unroll
                for (int k = 0; k < NK; ++k) {
                    const float tv = fmaf(hi, Wb[q][k].x, Wb[q][k].y);
                    const float rv = fmaxf(tv, 0.f);
                    hr[C + 1 + k] = fmaf(rv, rv, hr[C + 1 + k]);
                }
                if (t + 1 < NT) {              // refill slot q with step i+D
                    const float2* p = bptr + (size_t)(i + D) * (NK * 64);
                    #pragma unroll
                    for (int k = 0; k < NK; ++k)
                        Wb[q][k] = p[k * 64];
                }
            }
            __builtin_amdgcn_s_barrier();      // lockstep, no vmcnt drain
        }
    }
}

__global__ __launch_bounds__(256, 1)
void scan_kernel(const float2* __restrict__ wdg, const float2* __restrict__ wbk,
                 float* __restrict__ h) {
    const int lane = threadIdx.x & 63;
    const int wave = threadIdx.x >> 6;
    const int row  = blockIdx.x * 4 + wave;    // 256 blocks x 4 indep waves
    float* hrow = h + (size_t)row * HH;

    float hr[8];
    #pragma unroll
    for (int k = 0; k < 8; ++k) hr[k] = hrow[lane + 64 * k];

    scan_chunk<0>(wdg, wbk, hr, lane);
    scan_chunk<1>(wdg, wbk, hr, lane);
    scan_chunk<2>(wdg, wbk, hr, lane);
    scan_chunk<3>(wdg, wbk, hr, lane);
    scan_chunk<4>(wdg, wbk, hr, lane);
    scan_chunk<5>(wdg, wbk, hr, lane);
    scan_chunk<6>(wdg, wbk, hr, lane);
    scan_chunk<7>(wdg, wbk, hr, lane);

    #pragma unroll
    for (int k = 0; k < 8; ++k) hrow[lane + 64 * k] = hr[k];
}

// ---------------------------------------------------------------------------
// workspace layout (6.2 MB):
//   [0x000000, 0x040000) wdg  (512*64 f2 = 256 KB)
//   [0x040000, 0x120000) wbk  (114688 f2 = 896 KB)
//   [0x120000, 0x320000) h    (1024*512 fp32 = 2 MB)
//   [0x320000, 0x4A0000) Bin  (48*32*64 uint4 = 1.5 MB)
//   [0x4A0000, 0x620000) Bout (1.5 MB)
// ---------------------------------------------------------------------------
extern "C" void kernel_launch(void* const* d_in, const int* in_sizes, int n_in,
                              void* d_out, int out_size, void* d_ws, size_t ws_size,
                              hipStream_t stream) {
    const float* x     = (const float*)d_in[0];
    const float* W_in  = (const float*)d_in[1];
    const float* b_in  = (const float*)d_in[2];
    const float* W_hh  = (const float*)d_in[3];
    const float* b_hh  = (const float*)d_in[4];
    const float* W_out = (const float*)d_in[5];
    const float* b_out = (const float*)d_in[6];
    float* out = (float*)d_out;

    char* ws = (char*)d_ws;
    float2* wdg  = (float2*)ws;
    float2* wbk  = (float2*)(ws + 0x040000u);
    float*  h    = (float*)(ws + 0x120000u);
    uint4*  Bin  = (uint4*)(ws + 0x320000u);
    uint4*  Bout = (uint4*)(ws + 0x4A0000u);

    // 1) prep: scan-weight packs + W_in/W_out bf16 hi/lo frag-linear split
    prep_all<<<dim3(1344), dim3(256), 0, stream>>>(W_hh, b_hh, wdg, wbk,
                                                   W_in, Bin, W_out, Bout);

    // 2) h0 = relu^2(x @ W_in + b_in)  (A-side split fused into staging)
    mfma_gemm<true><<<dim3(16, 16), dim3(512), 0, stream>>>(x, Bin, b_in, h);

    // 3) sequential triangular scan, in-place on h
    scan_kernel<<<dim3(256), dim3(256), 0, stream>>>(wdg, wbk, h);

    // 4) out = h @ W_out + b_out  (A-side split fused into staging)
    mfma_gemm<false><<<dim3(16, 16), dim3(512), 0, stream>>>(h, Bout, b_out, out);
}